// Round 10
// baseline (1458.676 us; speedup 1.0000x reference)
//
#include <hip/hip_runtime.h>

// SJLT projection: out[b, idx[d,j]] += x[b,d]*sgn[d,j]; out *= 1/sqrt(8)
// B=32, D=1e6, P=4096, c=8.
//
// R18 post-mortem: 4-stage pipeline (pass_a+transpose+gather+reduce) stuck
// at 350-390us; every stage <55% VALU, <30% HBM -> structurally overhead-
// bound (8M entries touched 3x with LDS roundtrips each). R19: REWRITE.
// out = 512KB -> acc[8][4096] = 128KB fits LDS. One scatter kernel, grid
// 256 = 1 block/CU (zero tail, perfectly uniform work): block (bg,chunk)
// scans its d-chunk once; per entry 8x ds_add_f32 into LDS acc; dump 128KB
// partial. Reduce sums 64 chunk-partials. Deletes pass_a/transpose/gather/
// listA/xT. bg-major gid: all 4 bg-siblings of a chunk land on same XCD
// (gid%8 = chunk%8) -> idx/sgn re-reads are L2-shared. x read once, nt.
// R20 = R19 resubmit: container failed twice (infra), kernel never ran.
// Predict: scatter 50-80us, reduce ~8us, total ~100-160us.

#define D_TOTAL 1000000
#define PROJ    4096
#define C_SK    8
#define SCALE   0.35355339059327373f

#define NCHUNK  64
#define CHUNK_D (D_TOTAL / NCHUNK)   // 15625
#define NBG     4                    // batch groups of 8 rows each
#define SBLK    1024                 // scatter block size

// native clang vector types: __builtin_nontemporal_* accepts these
typedef int          ni4 __attribute__((ext_vector_type(4)));
typedef float        nf4 __attribute__((ext_vector_type(4)));

// ws layout: partial[NBG*NCHUNK][8*PROJ]
#define PART_SZ    ((size_t)NBG * NCHUNK * 8 * PROJ * 4)   // 33,554,432
#define WS_NEED    PART_SZ

// ---------------- K1: scatter into LDS accumulator ----------------
// grid 256 = bg(4) x chunk(64), bg-major: gid = bg*64 + chunk.
// Block: zero acc[8][4096] (128KB), scan chunk's 15625 d: per d load
// idx[8]+sgn[8] (L2-shared with bg-siblings) + 8 x-values (nt, coalesced),
// then 64 ds_add_f32 (bank = p%32, random -> ~2.8-pass). Flush to partial.
__global__ __launch_bounds__(1024)
void scatter_kernel(const float* __restrict__ x, const int* __restrict__ idx,
                    const int* __restrict__ sgn, float* __restrict__ partial) {
    __shared__ float acc[8 * PROJ];                // 131,072 B
    const int tid   = threadIdx.x;
    const int gid   = blockIdx.x;                  // [0, 256)
    const int bg    = gid >> 6;                    // 0..3
    const int chunk = gid & 63;                    // 0..63
    const int d0    = chunk * CHUNK_D;

    #pragma unroll
    for (int i = 0; i < 8; ++i)
        ((nf4*)acc)[tid + i * SBLK] = (nf4){0.f, 0.f, 0.f, 0.f};
    __syncthreads();

    const float* xb = x + (size_t)(bg * 8) * D_TOTAL;

    #pragma unroll 1
    for (int k = 0; k < (CHUNK_D + SBLK - 1) / SBLK; ++k) {
        const int dd = k * SBLK + tid;
        if (dd < CHUNK_D) {
            const int d = d0 + dd;
            // idx/sgn: shared with 3 sibling-bg blocks on this XCD -> cache
            const ni4 i0 = *(const ni4*)(idx + (size_t)d * C_SK);
            const ni4 i1 = *(const ni4*)(idx + (size_t)d * C_SK + 4);
            const ni4 s0 = *(const ni4*)(sgn + (size_t)d * C_SK);
            const ni4 s1 = *(const ni4*)(sgn + (size_t)d * C_SK + 4);
            // x: single-touch, nontemporal, coalesced per row
            unsigned xv[8];
            #pragma unroll
            for (int b = 0; b < 8; ++b)
                xv[b] = __builtin_nontemporal_load(
                    (const unsigned*)(xb + (size_t)b * D_TOTAL) + d);
            #pragma unroll
            for (int j = 0; j < 8; ++j) {
                const int      p  = (j < 4) ? i0[j] : i1[j - 4];
                const unsigned sb = ((unsigned)((j < 4) ? s0[j] : s1[j - 4]))
                                    & 0x80000000u;
                float* a = acc + p;
                #pragma unroll
                for (int b = 0; b < 8; ++b)
                    atomicAdd(a + b * PROJ, __uint_as_float(xv[b] ^ sb));
            }
        }
    }
    __syncthreads();

    float* dst = partial + (size_t)gid * (8 * PROJ);
    #pragma unroll
    for (int i = 0; i < 8; ++i) {
        const int o = tid + i * SBLK;
        __builtin_nontemporal_store(((const nf4*)acc)[o], (nf4*)dst + o);
    }
}

// ---------------- K2: reduce chunk-partials -> out ----------------
// out[b][p] = SCALE * sum_{c=0..63} partial[(b>>3)*64 + c][(b&7)*PROJ + p]
// thread = (b, p-quad); lanes read 1KB contiguous per iteration.
__global__ __launch_bounds__(256)
void reduce_scatter_kernel(const float* __restrict__ partial,
                           float* __restrict__ out) {
    const int t  = blockIdx.x * 256 + threadIdx.x;   // [0, 32768)
    const int p4 = t & 1023;                         // float4 index in row
    const int b  = t >> 10;                          // 0..31
    const int bg = b >> 3, lb = b & 7;
    const float* base = partial + (size_t)bg * 64 * (8 * PROJ)
                      + (size_t)lb * PROJ + (size_t)p4 * 4;
    nf4 s = {0.f, 0.f, 0.f, 0.f};
    #pragma unroll 4
    for (int c = 0; c < NCHUNK; ++c) {
        const nf4 v = __builtin_nontemporal_load(
            (const nf4*)(base + (size_t)c * (8 * PROJ)));
        s[0] += v[0]; s[1] += v[1]; s[2] += v[2]; s[3] += v[3];
    }
    s[0] *= SCALE; s[1] *= SCALE; s[2] *= SCALE; s[3] *= SCALE;
    *(nf4*)(out + (size_t)b * PROJ + (size_t)p4 * 4) = s;
}

// ---------------- fallback (R1 kernel) if ws too small ----------------
#define BG 8
#define FCHUNK 64
#define BLOCK 1024
__global__ __launch_bounds__(BLOCK, 4)
void sjlt_scatter_fallback(const float* __restrict__ x,
                           const int* __restrict__ idx,
                           const int* __restrict__ sgn,
                           float* __restrict__ out) {
    __shared__ float acc[BG * PROJ];
    const int tid = threadIdx.x;
    #pragma unroll
    for (int i = 0; i < (BG * PROJ) / BLOCK; ++i) acc[i * BLOCK + tid] = 0.0f;
    __syncthreads();
    const int chunk = D_TOTAL / FCHUNK;
    const int d0 = blockIdx.x * chunk;
    const int d1 = d0 + chunk;
    const int bg = blockIdx.y * BG;
    for (int d = d0 + tid; d < d1; d += BLOCK) {
        const int4 i0 = *(const int4*)(idx + (size_t)d * C_SK);
        const int4 i1 = *(const int4*)(idx + (size_t)d * C_SK + 4);
        const int4 s0 = *(const int4*)(sgn + (size_t)d * C_SK);
        const int4 s1 = *(const int4*)(sgn + (size_t)d * C_SK + 4);
        #pragma unroll
        for (int b = 0; b < BG; ++b) {
            const float xv = __builtin_nontemporal_load(x + (size_t)(bg + b) * D_TOTAL + d);
            const unsigned xb = __float_as_uint(xv);
            float* accb = acc + b * PROJ;
            atomicAdd(accb + i0.x, __uint_as_float(xb ^ ((unsigned)s0.x & 0x80000000u)));
            atomicAdd(accb + i0.y, __uint_as_float(xb ^ ((unsigned)s0.y & 0x80000000u)));
            atomicAdd(accb + i0.z, __uint_as_float(xb ^ ((unsigned)s0.z & 0x80000000u)));
            atomicAdd(accb + i0.w, __uint_as_float(xb ^ ((unsigned)s0.w & 0x80000000u)));
            atomicAdd(accb + i1.x, __uint_as_float(xb ^ ((unsigned)s1.x & 0x80000000u)));
            atomicAdd(accb + i1.y, __uint_as_float(xb ^ ((unsigned)s1.y & 0x80000000u)));
            atomicAdd(accb + i1.z, __uint_as_float(xb ^ ((unsigned)s1.z & 0x80000000u)));
            atomicAdd(accb + i1.w, __uint_as_float(xb ^ ((unsigned)s1.w & 0x80000000u)));
        }
    }
    __syncthreads();
    #pragma unroll
    for (int i = 0; i < (BG * PROJ) / BLOCK; ++i) {
        const int lin = i * BLOCK + tid;
        const int b = lin >> 12;
        const int pp = lin & (PROJ - 1);
        unsafeAtomicAdd(out + (size_t)(bg + b) * PROJ + pp, acc[lin] * SCALE);
    }
}

extern "C" void kernel_launch(void* const* d_in, const int* in_sizes, int n_in,
                              void* d_out, int out_size, void* d_ws, size_t ws_size,
                              hipStream_t stream) {
    const float* x   = (const float*)d_in[0];
    const int*   idx = (const int*)d_in[1];
    const int*   sgn = (const int*)d_in[2];
    float*       out = (float*)d_out;

    if (ws_size < WS_NEED) {
        (void)hipMemsetAsync(out, 0, (size_t)out_size * sizeof(float), stream);
        dim3 grid(FCHUNK, 32 / BG);
        sjlt_scatter_fallback<<<grid, BLOCK, 0, stream>>>(x, idx, sgn, out);
        return;
    }

    float* partial = (float*)d_ws;
    scatter_kernel<<<NBG * NCHUNK, SBLK, 0, stream>>>(x, idx, sgn, partial);
    reduce_scatter_kernel<<<(32 * PROJ / 4) / 256, 256, 0, stream>>>(partial, out);
}